// Round 1
// baseline (914.432 us; speedup 1.0000x reference)
//
#include <hip/hip_runtime.h>
#include <stdint.h>

#define N_NODES 200000
#define N_EDGES 600000

typedef __attribute__((ext_vector_type(8))) short short8;
typedef __attribute__((ext_vector_type(4))) float floatx4;

static __device__ __forceinline__ unsigned short f2bf(float f) {
  union { float f; unsigned u; } c; c.f = f;
  unsigned u = c.u;
  unsigned r = (u + 0x7fffu + ((u >> 16) & 1u)) >> 16;
  return (unsigned short)r;
}

// ---------------- weight prep: f32 [128][128] -> bf16 transposed [n][k] ----------------
__global__ __launch_bounds__(256) void prep_kernel(
    const float* w0, const float* w1, const float* w2, const float* w3, const float* w4,
    unsigned short* out) {
  const float* src;
  switch (blockIdx.y) {
    case 0: src = w0; break;
    case 1: src = w1; break;
    case 2: src = w2; break;
    case 3: src = w3; break;
    default: src = w4; break;
  }
  unsigned short* dst = out + (size_t)blockIdx.y * 16384;
  int t = blockIdx.x * 256 + threadIdx.x;  // 0..4095
#pragma unroll
  for (int i = 0; i < 4; ++i) {
    int idx = t + 4096 * i;  // idx = n*128 + k
    int n = idx >> 7, k = idx & 127;
    dst[idx] = f2bf(src[k * 128 + n]);
  }
}

// ---------------- CSR build ----------------
__global__ __launch_bounds__(256) void hist_kernel(const int* __restrict__ dst, int* deg, int E) {
  int e = blockIdx.x * 256 + threadIdx.x;
  if (e < E) atomicAdd(&deg[dst[e]], 1);
}

// in-place exclusive scan of deg (stored in off[0..n-1]) -> off[0..n], also copies to cursor
__global__ __launch_bounds__(1024) void scan_kernel(int* off, int* cursor, int n) {
  __shared__ int wsums[16];
  __shared__ int sbase[17];
  const int tid = threadIdx.x, lane = tid & 63, wid = tid >> 6;
  int running = 0;
  for (int base = 0; base < n; base += 8192) {
    int idx0 = base + tid * 8;
    int v[8];
    int s = 0;
#pragma unroll
    for (int j = 0; j < 8; ++j) {
      int ix = idx0 + j;
      v[j] = (ix < n) ? off[ix] : 0;
      s += v[j];
    }
    int incl = s;
#pragma unroll
    for (int d = 1; d < 64; d <<= 1) {
      int t = __shfl_up(incl, d, 64);
      if (lane >= d) incl += t;
    }
    if (lane == 63) wsums[wid] = incl;
    __syncthreads();
    if (tid == 0) {
      int acc = 0;
      for (int w = 0; w < 16; ++w) { sbase[w] = acc; acc += wsums[w]; }
      sbase[16] = acc;
    }
    __syncthreads();
    int excl = running + sbase[wid] + (incl - s);
#pragma unroll
    for (int j = 0; j < 8; ++j) {
      int ix = idx0 + j;
      if (ix < n) { off[ix] = excl; cursor[ix] = excl; }
      excl += v[j];
    }
    running += sbase[16];
    __syncthreads();
  }
  if (tid == 0) off[n] = running;
}

__global__ __launch_bounds__(256) void scatter_kernel(const int* __restrict__ dst, int* cursor,
                                                      int* eids, int E) {
  int e = blockIdx.x * 256 + threadIdx.x;
  if (e < E) {
    int p = atomicAdd(&cursor[dst[e]], 1);
    eids[p] = e;
  }
}

// ---------------- aggregation + z = (1+eps)*h + sum relu(h[src]+ef) ----------------
// one wave per node; lane handles channels (2*lane, 2*lane+1); We kept in registers
__global__ __launch_bounds__(256) void agg_z_kernel(
    const float* __restrict__ h, const int* __restrict__ off, const int* __restrict__ eids,
    const int* __restrict__ srcIdx, const float* __restrict__ edge_attr,
    const float* __restrict__ We, const float* __restrict__ be,
    const float* __restrict__ epsPtr, unsigned short* __restrict__ z) {
  const int lane = threadIdx.x & 63;
  const int wv = threadIdx.x >> 6;
  const int c = lane * 2;
  float2 wr[16];
#pragma unroll
  for (int d = 0; d < 16; ++d) wr[d] = *((const float2*)(We + d * 128 + c));
  const float2 bev = *((const float2*)(be + c));
  const float epsp = 1.0f + epsPtr[0];
  const int waveId = blockIdx.x * 4 + wv;
  const int nWaves = gridDim.x * 4;
  for (int node = waveId; node < N_NODES; node += nWaves) {
    float accx = 0.0f, accy = 0.0f;
    const int s0 = off[node], s1 = off[node + 1];
    for (int ii = s0; ii < s1; ++ii) {
      int e = __builtin_amdgcn_readfirstlane(eids[ii]);
      int sn = __builtin_amdgcn_readfirstlane(srcIdx[e]);
      const float2 hv = *((const float2*)(h + (size_t)sn * 128 + c));
      const float4 q0 = *((const float4*)(edge_attr + (size_t)e * 16));
      const float4 q1 = *((const float4*)(edge_attr + (size_t)e * 16 + 4));
      const float4 q2 = *((const float4*)(edge_attr + (size_t)e * 16 + 8));
      const float4 q3 = *((const float4*)(edge_attr + (size_t)e * 16 + 12));
      float efx = bev.x, efy = bev.y;
      efx += q0.x * wr[0].x; efy += q0.x * wr[0].y;
      efx += q0.y * wr[1].x; efy += q0.y * wr[1].y;
      efx += q0.z * wr[2].x; efy += q0.z * wr[2].y;
      efx += q0.w * wr[3].x; efy += q0.w * wr[3].y;
      efx += q1.x * wr[4].x; efy += q1.x * wr[4].y;
      efx += q1.y * wr[5].x; efy += q1.y * wr[5].y;
      efx += q1.z * wr[6].x; efy += q1.z * wr[6].y;
      efx += q1.w * wr[7].x; efy += q1.w * wr[7].y;
      efx += q2.x * wr[8].x; efy += q2.x * wr[8].y;
      efx += q2.y * wr[9].x; efy += q2.y * wr[9].y;
      efx += q2.z * wr[10].x; efy += q2.z * wr[10].y;
      efx += q2.w * wr[11].x; efy += q2.w * wr[11].y;
      efx += q3.x * wr[12].x; efy += q3.x * wr[12].y;
      efx += q3.y * wr[13].x; efy += q3.y * wr[13].y;
      efx += q3.z * wr[14].x; efy += q3.z * wr[14].y;
      efx += q3.w * wr[15].x; efy += q3.w * wr[15].y;
      accx += fmaxf(hv.x + efx, 0.0f);
      accy += fmaxf(hv.y + efy, 0.0f);
    }
    const float2 hn = *((const float2*)(h + (size_t)node * 128 + c));
    unsigned p = (unsigned)f2bf(epsp * hn.x + accx) |
                 ((unsigned)f2bf(epsp * hn.y + accy) << 16);
    *((unsigned*)(z + (size_t)node * 128 + c)) = p;
  }
}

// ---------------- fused (1 or 2)-layer MLP GEMM, M-tile=64, N=K=128, bf16 MFMA ----------------
__global__ __launch_bounds__(256) void mlp_kernel(
    const void* __restrict__ Ain, int aIsBf16,
    const unsigned short* __restrict__ W1t, const float* __restrict__ b1,
    const unsigned short* __restrict__ W2t, const float* __restrict__ b2,
    int twoStage, float* __restrict__ out) {
  __shared__ unsigned short sA[64][136];
  __shared__ unsigned short sW[128][136];
  const int tid = threadIdx.x;
  const int lane = tid & 63;
  const int wv = tid >> 6;
  const int lr = lane & 15, quad = lane >> 4;
  const int mw = wv >> 1, nw = wv & 1;
  const size_t rowBase = (size_t)blockIdx.x * 64;

  if (aIsBf16) {
    const uint4* src = (const uint4*)((const unsigned short*)Ain + rowBase * 128);
#pragma unroll
    for (int i = 0; i < 4; ++i) {
      int idx = tid + 256 * i;  // 0..1023 chunks of 8 bf16
      int r = idx >> 4, c8 = idx & 15;
      uint4 v = src[idx];
      *((uint4*)&sA[r][c8 * 8]) = v;
    }
  } else {
    const float4* src = (const float4*)((const float*)Ain + rowBase * 128);
#pragma unroll
    for (int i = 0; i < 8; ++i) {
      int idx = tid + 256 * i;  // 0..2047 float4
      int r = idx >> 5, c4 = idx & 31;
      float4 v = src[idx];
      uint2 p;
      p.x = (unsigned)f2bf(v.x) | ((unsigned)f2bf(v.y) << 16);
      p.y = (unsigned)f2bf(v.z) | ((unsigned)f2bf(v.w) << 16);
      *((uint2*)&sA[r][c4 * 4]) = p;
    }
  }
  {
    const uint4* srcw = (const uint4*)W1t;
#pragma unroll
    for (int i = 0; i < 8; ++i) {
      int idx = tid + 256 * i;  // 0..2047 chunks of 8 bf16
      int r = idx >> 4, c8 = idx & 15;
      *((uint4*)&sW[r][c8 * 8]) = srcw[idx];
    }
  }
  __syncthreads();

  floatx4 acc[2][4];
#pragma unroll
  for (int mi = 0; mi < 2; ++mi)
#pragma unroll
    for (int ni = 0; ni < 4; ++ni)
#pragma unroll
      for (int i = 0; i < 4; ++i) acc[mi][ni][i] = 0.0f;

#pragma unroll
  for (int kk = 0; kk < 4; ++kk) {
    short8 a[2], b[4];
#pragma unroll
    for (int mi = 0; mi < 2; ++mi)
      a[mi] = *((const short8*)&sA[32 * mw + 16 * mi + lr][kk * 32 + quad * 8]);
#pragma unroll
    for (int ni = 0; ni < 4; ++ni)
      b[ni] = *((const short8*)&sW[64 * nw + 16 * ni + lr][kk * 32 + quad * 8]);
#pragma unroll
    for (int mi = 0; mi < 2; ++mi)
#pragma unroll
      for (int ni = 0; ni < 4; ++ni)
        acc[mi][ni] = __builtin_amdgcn_mfma_f32_16x16x32_bf16(a[mi], b[ni], acc[mi][ni], 0, 0, 0);
  }

  if (!twoStage) {
#pragma unroll
    for (int mi = 0; mi < 2; ++mi)
#pragma unroll
      for (int ni = 0; ni < 4; ++ni)
#pragma unroll
        for (int i = 0; i < 4; ++i) {
          int row = 32 * mw + 16 * mi + quad * 4 + i;
          int col = 64 * nw + 16 * ni + lr;
          out[(rowBase + row) * 128 + col] = fmaxf(acc[mi][ni][i] + b1[col], 0.0f);
        }
    return;
  }

  __syncthreads();  // all stage-1 LDS reads done
  // write t = relu(z@W1+b1) into sA as bf16
#pragma unroll
  for (int mi = 0; mi < 2; ++mi)
#pragma unroll
    for (int ni = 0; ni < 4; ++ni)
#pragma unroll
      for (int i = 0; i < 4; ++i) {
        int row = 32 * mw + 16 * mi + quad * 4 + i;
        int col = 64 * nw + 16 * ni + lr;
        sA[row][col] = f2bf(fmaxf(acc[mi][ni][i] + b1[col], 0.0f));
      }
  // reload W2t
  {
    const uint4* srcw = (const uint4*)W2t;
#pragma unroll
    for (int i = 0; i < 8; ++i) {
      int idx = tid + 256 * i;
      int r = idx >> 4, c8 = idx & 15;
      *((uint4*)&sW[r][c8 * 8]) = srcw[idx];
    }
  }
  __syncthreads();

  floatx4 acc2[2][4];
#pragma unroll
  for (int mi = 0; mi < 2; ++mi)
#pragma unroll
    for (int ni = 0; ni < 4; ++ni)
#pragma unroll
      for (int i = 0; i < 4; ++i) acc2[mi][ni][i] = 0.0f;

#pragma unroll
  for (int kk = 0; kk < 4; ++kk) {
    short8 a[2], b[4];
#pragma unroll
    for (int mi = 0; mi < 2; ++mi)
      a[mi] = *((const short8*)&sA[32 * mw + 16 * mi + lr][kk * 32 + quad * 8]);
#pragma unroll
    for (int ni = 0; ni < 4; ++ni)
      b[ni] = *((const short8*)&sW[64 * nw + 16 * ni + lr][kk * 32 + quad * 8]);
#pragma unroll
    for (int mi = 0; mi < 2; ++mi)
#pragma unroll
      for (int ni = 0; ni < 4; ++ni)
        acc2[mi][ni] = __builtin_amdgcn_mfma_f32_16x16x32_bf16(a[mi], b[ni], acc2[mi][ni], 0, 0, 0);
  }

#pragma unroll
  for (int mi = 0; mi < 2; ++mi)
#pragma unroll
    for (int ni = 0; ni < 4; ++ni)
#pragma unroll
      for (int i = 0; i < 4; ++i) {
        int row = 32 * mw + 16 * mi + quad * 4 + i;
        int col = 64 * nw + 16 * ni + lr;
        out[(rowBase + row) * 128 + col] = fmaxf(acc2[mi][ni][i] + b2[col], 0.0f);
      }
}

extern "C" void kernel_launch(void* const* d_in, const int* in_sizes, int n_in,
                              void* d_out, int out_size, void* d_ws, size_t ws_size,
                              hipStream_t stream) {
  (void)in_sizes; (void)n_in; (void)out_size; (void)ws_size;
  const float* x = (const float*)d_in[0];
  const int* eidx = (const int*)d_in[1];
  const int* esrc = eidx;
  const int* edst = eidx + N_EDGES;
  const float* eattr = (const float*)d_in[2];
  const float* W_enc = (const float*)d_in[3];
  const float* b_enc = (const float*)d_in[4];
  const float* We1 = (const float*)d_in[5];
  const float* be1 = (const float*)d_in[6];
  const float* W11 = (const float*)d_in[7];
  const float* b11 = (const float*)d_in[8];
  const float* W12 = (const float*)d_in[9];
  const float* b12 = (const float*)d_in[10];
  const float* eps1 = (const float*)d_in[11];
  const float* We2 = (const float*)d_in[12];
  const float* be2 = (const float*)d_in[13];
  const float* W21 = (const float*)d_in[14];
  const float* b21 = (const float*)d_in[15];
  const float* W22 = (const float*)d_in[16];
  const float* b22 = (const float*)d_in[17];
  const float* eps2 = (const float*)d_in[18];

  char* ws = (char*)d_ws;
  unsigned short* wt = (unsigned short*)ws;                                   // 163840 B
  float* bufA = (float*)(ws + 163840);                                        // 102,400,000 B
  unsigned short* bufZ = (unsigned short*)(ws + 163840 + 102400000ull);       // 51,200,000 B
  int* off = (int*)(ws + 163840 + 102400000ull + 51200000ull);                // (N+1)*4
  int* cursor = off + (N_NODES + 1);
  int* eids = cursor + N_NODES;

  unsigned short* Wt_enc = wt;
  unsigned short* Wt11 = wt + 16384;
  unsigned short* Wt12 = wt + 2 * 16384;
  unsigned short* Wt21 = wt + 3 * 16384;
  unsigned short* Wt22 = wt + 4 * 16384;

  hipMemsetAsync(off, 0, (N_NODES + 1) * sizeof(int), stream);
  prep_kernel<<<dim3(16, 5), 256, 0, stream>>>(W_enc, W11, W12, W21, W22, wt);

  // h0 = relu(x @ W_enc + b_enc)
  mlp_kernel<<<3125, 256, 0, stream>>>(x, 0, Wt_enc, b_enc, Wt_enc, b_enc, 0, bufA);

  hist_kernel<<<(N_EDGES + 255) / 256, 256, 0, stream>>>(edst, off, N_EDGES);
  scan_kernel<<<1, 1024, 0, stream>>>(off, cursor, N_NODES);
  scatter_kernel<<<(N_EDGES + 255) / 256, 256, 0, stream>>>(edst, cursor, eids, N_EDGES);

  // conv1
  agg_z_kernel<<<4096, 256, 0, stream>>>(bufA, off, eids, esrc, eattr, We1, be1, eps1, bufZ);
  mlp_kernel<<<3125, 256, 0, stream>>>(bufZ, 1, Wt11, b11, Wt12, b12, 1, bufA);
  // conv2
  agg_z_kernel<<<4096, 256, 0, stream>>>(bufA, off, eids, esrc, eattr, We2, be2, eps2, bufZ);
  mlp_kernel<<<3125, 256, 0, stream>>>(bufZ, 1, Wt21, b21, Wt22, b22, 1, (float*)d_out);
}

// Round 2
// 659.834 us; speedup vs baseline: 1.3859x; 1.3859x over previous
//
#include <hip/hip_runtime.h>
#include <stdint.h>

#define N_NODES 200000
#define N_EDGES 600000
#define SCAN_CHUNK 1024
#define SCAN_BLOCKS ((N_NODES + SCAN_CHUNK - 1) / SCAN_CHUNK)  // 196

typedef __attribute__((ext_vector_type(8))) short short8;
typedef __attribute__((ext_vector_type(4))) float floatx4;

static __device__ __forceinline__ unsigned short f2bf(float f) {
  union { float f; unsigned u; } c; c.f = f;
  unsigned u = c.u;
  unsigned r = (u + 0x7fffu + ((u >> 16) & 1u)) >> 16;
  return (unsigned short)r;
}

// ---------------- weight prep: f32 [128][128] -> bf16 transposed [n][k] ----------------
__global__ __launch_bounds__(256) void prep_kernel(
    const float* w0, const float* w1, const float* w2, const float* w3, const float* w4,
    unsigned short* out) {
  const float* src;
  switch (blockIdx.y) {
    case 0: src = w0; break;
    case 1: src = w1; break;
    case 2: src = w2; break;
    case 3: src = w3; break;
    default: src = w4; break;
  }
  unsigned short* dst = out + (size_t)blockIdx.y * 16384;
  int t = blockIdx.x * 256 + threadIdx.x;  // 0..4095
#pragma unroll
  for (int i = 0; i < 4; ++i) {
    int idx = t + 4096 * i;  // idx = n*128 + k
    int n = idx >> 7, k = idx & 127;
    dst[idx] = f2bf(src[k * 128 + n]);
  }
}

// ---------------- CSR build ----------------
__global__ __launch_bounds__(256) void hist_kernel(const int* __restrict__ dst, int* deg, int E) {
  int e = blockIdx.x * 256 + threadIdx.x;
  if (e < E) atomicAdd(&deg[dst[e]], 1);
}

// pass 1: per-block partial sums of deg
__global__ __launch_bounds__(256) void scan_sum_kernel(const int* __restrict__ deg, int* partial,
                                                       int n) {
  __shared__ int wsum[4];
  const int tid = threadIdx.x, lane = tid & 63, wid = tid >> 6;
  int idx0 = blockIdx.x * SCAN_CHUNK + tid * 4;
  int s = 0;
#pragma unroll
  for (int j = 0; j < 4; ++j) {
    int ix = idx0 + j;
    if (ix < n) s += deg[ix];
  }
#pragma unroll
  for (int d = 32; d >= 1; d >>= 1) s += __shfl_down(s, d, 64);
  if (lane == 0) wsum[wid] = s;
  __syncthreads();
  if (tid == 0) partial[blockIdx.x] = wsum[0] + wsum[1] + wsum[2] + wsum[3];
}

// pass 2: single-block exclusive scan of partials (nb <= 256), writes off[n]=total
__global__ __launch_bounds__(256) void scan_partials_kernel(int* partial, int* off, int nb, int n) {
  __shared__ int wsum[4];
  const int tid = threadIdx.x, lane = tid & 63, wid = tid >> 6;
  int val = (tid < nb) ? partial[tid] : 0;
  int incl = val;
#pragma unroll
  for (int d = 1; d < 64; d <<= 1) {
    int t = __shfl_up(incl, d, 64);
    if (lane >= d) incl += t;
  }
  if (lane == 63) wsum[wid] = incl;
  __syncthreads();
  int base = 0;
  for (int w = 0; w < wid; ++w) base += wsum[w];
  int excl = base + incl - val;
  if (tid < nb) partial[tid] = excl;
  if (tid == 0) off[n] = wsum[0] + wsum[1] + wsum[2] + wsum[3];
}

// pass 3: per-block local exclusive scan + block base; writes off[] and cursor[]
__global__ __launch_bounds__(256) void scan_apply_kernel(const int* __restrict__ partial, int* off,
                                                         int* cursor, int n) {
  __shared__ int wsum[4];
  const int tid = threadIdx.x, lane = tid & 63, wid = tid >> 6;
  int idx0 = blockIdx.x * SCAN_CHUNK + tid * 4;
  int v[4];
  int s = 0;
#pragma unroll
  for (int j = 0; j < 4; ++j) {
    int ix = idx0 + j;
    v[j] = (ix < n) ? off[ix] : 0;
    s += v[j];
  }
  int incl = s;
#pragma unroll
  for (int d = 1; d < 64; d <<= 1) {
    int t = __shfl_up(incl, d, 64);
    if (lane >= d) incl += t;
  }
  if (lane == 63) wsum[wid] = incl;
  __syncthreads();
  int base = partial[blockIdx.x];
  for (int w = 0; w < wid; ++w) base += wsum[w];
  int running = base + incl - s;
#pragma unroll
  for (int j = 0; j < 4; ++j) {
    int ix = idx0 + j;
    if (ix < n) { off[ix] = running; cursor[ix] = running; }
    running += v[j];
  }
}

__global__ __launch_bounds__(256) void scatter_kernel(const int* __restrict__ dst, int* cursor,
                                                      int* eids, int E) {
  int e = blockIdx.x * 256 + threadIdx.x;
  if (e < E) {
    int p = atomicAdd(&cursor[dst[e]], 1);
    eids[p] = e;
  }
}

// ---------------- aggregation + z = (1+eps)*h + sum relu(h[src]+ef) ----------------
// one wave per node; lane handles channels (2*lane, 2*lane+1); We kept in registers
__global__ __launch_bounds__(256) void agg_z_kernel(
    const float* __restrict__ h, const int* __restrict__ off, const int* __restrict__ eids,
    const int* __restrict__ srcIdx, const float* __restrict__ edge_attr,
    const float* __restrict__ We, const float* __restrict__ be,
    const float* __restrict__ epsPtr, unsigned short* __restrict__ z) {
  const int lane = threadIdx.x & 63;
  const int wv = threadIdx.x >> 6;
  const int c = lane * 2;
  float2 wr[16];
#pragma unroll
  for (int d = 0; d < 16; ++d) wr[d] = *((const float2*)(We + d * 128 + c));
  const float2 bev = *((const float2*)(be + c));
  const float epsp = 1.0f + epsPtr[0];
  const int waveId = blockIdx.x * 4 + wv;
  const int nWaves = gridDim.x * 4;
  for (int node = waveId; node < N_NODES; node += nWaves) {
    float accx = 0.0f, accy = 0.0f;
    const int s0 = off[node], s1 = off[node + 1];
    for (int ii = s0; ii < s1; ++ii) {
      int e = __builtin_amdgcn_readfirstlane(eids[ii]);
      int sn = __builtin_amdgcn_readfirstlane(srcIdx[e]);
      const float2 hv = *((const float2*)(h + (size_t)sn * 128 + c));
      const float4 q0 = *((const float4*)(edge_attr + (size_t)e * 16));
      const float4 q1 = *((const float4*)(edge_attr + (size_t)e * 16 + 4));
      const float4 q2 = *((const float4*)(edge_attr + (size_t)e * 16 + 8));
      const float4 q3 = *((const float4*)(edge_attr + (size_t)e * 16 + 12));
      float efx = bev.x, efy = bev.y;
      efx += q0.x * wr[0].x; efy += q0.x * wr[0].y;
      efx += q0.y * wr[1].x; efy += q0.y * wr[1].y;
      efx += q0.z * wr[2].x; efy += q0.z * wr[2].y;
      efx += q0.w * wr[3].x; efy += q0.w * wr[3].y;
      efx += q1.x * wr[4].x; efy += q1.x * wr[4].y;
      efx += q1.y * wr[5].x; efy += q1.y * wr[5].y;
      efx += q1.z * wr[6].x; efy += q1.z * wr[6].y;
      efx += q1.w * wr[7].x; efy += q1.w * wr[7].y;
      efx += q2.x * wr[8].x; efy += q2.x * wr[8].y;
      efx += q2.y * wr[9].x; efy += q2.y * wr[9].y;
      efx += q2.z * wr[10].x; efy += q2.z * wr[10].y;
      efx += q2.w * wr[11].x; efy += q2.w * wr[11].y;
      efx += q3.x * wr[12].x; efy += q3.x * wr[12].y;
      efx += q3.y * wr[13].x; efy += q3.y * wr[13].y;
      efx += q3.z * wr[14].x; efy += q3.z * wr[14].y;
      efx += q3.w * wr[15].x; efy += q3.w * wr[15].y;
      accx += fmaxf(hv.x + efx, 0.0f);
      accy += fmaxf(hv.y + efy, 0.0f);
    }
    const float2 hn = *((const float2*)(h + (size_t)node * 128 + c));
    unsigned p = (unsigned)f2bf(epsp * hn.x + accx) |
                 ((unsigned)f2bf(epsp * hn.y + accy) << 16);
    *((unsigned*)(z + (size_t)node * 128 + c)) = p;
  }
}

// ---------------- fused (1 or 2)-layer MLP GEMM, M-tile=64, N=K=128, bf16 MFMA ----------------
__global__ __launch_bounds__(256) void mlp_kernel(
    const void* __restrict__ Ain, int aIsBf16,
    const unsigned short* __restrict__ W1t, const float* __restrict__ b1,
    const unsigned short* __restrict__ W2t, const float* __restrict__ b2,
    int twoStage, float* __restrict__ out) {
  __shared__ unsigned short sA[64][136];
  __shared__ unsigned short sW[128][136];
  const int tid = threadIdx.x;
  const int lane = tid & 63;
  const int wv = tid >> 6;
  const int lr = lane & 15, quad = lane >> 4;
  const int mw = wv >> 1, nw = wv & 1;
  const size_t rowBase = (size_t)blockIdx.x * 64;

  if (aIsBf16) {
    const uint4* src = (const uint4*)((const unsigned short*)Ain + rowBase * 128);
#pragma unroll
    for (int i = 0; i < 4; ++i) {
      int idx = tid + 256 * i;  // 0..1023 chunks of 8 bf16
      int r = idx >> 4, c8 = idx & 15;
      uint4 v = src[idx];
      *((uint4*)&sA[r][c8 * 8]) = v;
    }
  } else {
    const float4* src = (const float4*)((const float*)Ain + rowBase * 128);
#pragma unroll
    for (int i = 0; i < 8; ++i) {
      int idx = tid + 256 * i;  // 0..2047 float4
      int r = idx >> 5, c4 = idx & 31;
      float4 v = src[idx];
      uint2 p;
      p.x = (unsigned)f2bf(v.x) | ((unsigned)f2bf(v.y) << 16);
      p.y = (unsigned)f2bf(v.z) | ((unsigned)f2bf(v.w) << 16);
      *((uint2*)&sA[r][c4 * 4]) = p;
    }
  }
  {
    const uint4* srcw = (const uint4*)W1t;
#pragma unroll
    for (int i = 0; i < 8; ++i) {
      int idx = tid + 256 * i;  // 0..2047 chunks of 8 bf16
      int r = idx >> 4, c8 = idx & 15;
      *((uint4*)&sW[r][c8 * 8]) = srcw[idx];
    }
  }
  __syncthreads();

  floatx4 acc[2][4];
#pragma unroll
  for (int mi = 0; mi < 2; ++mi)
#pragma unroll
    for (int ni = 0; ni < 4; ++ni)
#pragma unroll
      for (int i = 0; i < 4; ++i) acc[mi][ni][i] = 0.0f;

#pragma unroll
  for (int kk = 0; kk < 4; ++kk) {
    short8 a[2], b[4];
#pragma unroll
    for (int mi = 0; mi < 2; ++mi)
      a[mi] = *((const short8*)&sA[32 * mw + 16 * mi + lr][kk * 32 + quad * 8]);
#pragma unroll
    for (int ni = 0; ni < 4; ++ni)
      b[ni] = *((const short8*)&sW[64 * nw + 16 * ni + lr][kk * 32 + quad * 8]);
#pragma unroll
    for (int mi = 0; mi < 2; ++mi)
#pragma unroll
      for (int ni = 0; ni < 4; ++ni)
        acc[mi][ni] = __builtin_amdgcn_mfma_f32_16x16x32_bf16(a[mi], b[ni], acc[mi][ni], 0, 0, 0);
  }

  if (!twoStage) {
#pragma unroll
    for (int mi = 0; mi < 2; ++mi)
#pragma unroll
      for (int ni = 0; ni < 4; ++ni)
#pragma unroll
        for (int i = 0; i < 4; ++i) {
          int row = 32 * mw + 16 * mi + quad * 4 + i;
          int col = 64 * nw + 16 * ni + lr;
          out[(rowBase + row) * 128 + col] = fmaxf(acc[mi][ni][i] + b1[col], 0.0f);
        }
    return;
  }

  __syncthreads();  // all stage-1 LDS reads done
  // write t = relu(z@W1+b1) into sA as bf16
#pragma unroll
  for (int mi = 0; mi < 2; ++mi)
#pragma unroll
    for (int ni = 0; ni < 4; ++ni)
#pragma unroll
      for (int i = 0; i < 4; ++i) {
        int row = 32 * mw + 16 * mi + quad * 4 + i;
        int col = 64 * nw + 16 * ni + lr;
        sA[row][col] = f2bf(fmaxf(acc[mi][ni][i] + b1[col], 0.0f));
      }
  // reload W2t
  {
    const uint4* srcw = (const uint4*)W2t;
#pragma unroll
    for (int i = 0; i < 8; ++i) {
      int idx = tid + 256 * i;
      int r = idx >> 4, c8 = idx & 15;
      *((uint4*)&sW[r][c8 * 8]) = srcw[idx];
    }
  }
  __syncthreads();

  floatx4 acc2[2][4];
#pragma unroll
  for (int mi = 0; mi < 2; ++mi)
#pragma unroll
    for (int ni = 0; ni < 4; ++ni)
#pragma unroll
      for (int i = 0; i < 4; ++i) acc2[mi][ni][i] = 0.0f;

#pragma unroll
  for (int kk = 0; kk < 4; ++kk) {
    short8 a[2], b[4];
#pragma unroll
    for (int mi = 0; mi < 2; ++mi)
      a[mi] = *((const short8*)&sA[32 * mw + 16 * mi + lr][kk * 32 + quad * 8]);
#pragma unroll
    for (int ni = 0; ni < 4; ++ni)
      b[ni] = *((const short8*)&sW[64 * nw + 16 * ni + lr][kk * 32 + quad * 8]);
#pragma unroll
    for (int mi = 0; mi < 2; ++mi)
#pragma unroll
      for (int ni = 0; ni < 4; ++ni)
        acc2[mi][ni] = __builtin_amdgcn_mfma_f32_16x16x32_bf16(a[mi], b[ni], acc2[mi][ni], 0, 0, 0);
  }

#pragma unroll
  for (int mi = 0; mi < 2; ++mi)
#pragma unroll
    for (int ni = 0; ni < 4; ++ni)
#pragma unroll
      for (int i = 0; i < 4; ++i) {
        int row = 32 * mw + 16 * mi + quad * 4 + i;
        int col = 64 * nw + 16 * ni + lr;
        out[(rowBase + row) * 128 + col] = fmaxf(acc2[mi][ni][i] + b2[col], 0.0f);
      }
}

extern "C" void kernel_launch(void* const* d_in, const int* in_sizes, int n_in,
                              void* d_out, int out_size, void* d_ws, size_t ws_size,
                              hipStream_t stream) {
  (void)in_sizes; (void)n_in; (void)out_size; (void)ws_size;
  const float* x = (const float*)d_in[0];
  const int* eidx = (const int*)d_in[1];
  const int* esrc = eidx;
  const int* edst = eidx + N_EDGES;
  const float* eattr = (const float*)d_in[2];
  const float* W_enc = (const float*)d_in[3];
  const float* b_enc = (const float*)d_in[4];
  const float* We1 = (const float*)d_in[5];
  const float* be1 = (const float*)d_in[6];
  const float* W11 = (const float*)d_in[7];
  const float* b11 = (const float*)d_in[8];
  const float* W12 = (const float*)d_in[9];
  const float* b12 = (const float*)d_in[10];
  const float* eps1 = (const float*)d_in[11];
  const float* We2 = (const float*)d_in[12];
  const float* be2 = (const float*)d_in[13];
  const float* W21 = (const float*)d_in[14];
  const float* b21 = (const float*)d_in[15];
  const float* W22 = (const float*)d_in[16];
  const float* b22 = (const float*)d_in[17];
  const float* eps2 = (const float*)d_in[18];

  char* ws = (char*)d_ws;
  unsigned short* wt = (unsigned short*)ws;                                   // 163840 B
  float* bufA = (float*)(ws + 163840);                                        // 102,400,000 B
  unsigned short* bufZ = (unsigned short*)(ws + 163840 + 102400000ull);       // 51,200,000 B
  int* off = (int*)(ws + 163840 + 102400000ull + 51200000ull);                // (N+1)*4
  int* cursor = off + (N_NODES + 1);
  int* eids = cursor + N_NODES;
  int* partial = eids + N_EDGES;  // SCAN_BLOCKS ints

  unsigned short* Wt_enc = wt;
  unsigned short* Wt11 = wt + 16384;
  unsigned short* Wt12 = wt + 2 * 16384;
  unsigned short* Wt21 = wt + 3 * 16384;
  unsigned short* Wt22 = wt + 4 * 16384;

  hipMemsetAsync(off, 0, (N_NODES + 1) * sizeof(int), stream);
  prep_kernel<<<dim3(16, 5), 256, 0, stream>>>(W_enc, W11, W12, W21, W22, wt);

  // h0 = relu(x @ W_enc + b_enc)
  mlp_kernel<<<3125, 256, 0, stream>>>(x, 0, Wt_enc, b_enc, Wt_enc, b_enc, 0, bufA);

  hist_kernel<<<(N_EDGES + 255) / 256, 256, 0, stream>>>(edst, off, N_EDGES);
  scan_sum_kernel<<<SCAN_BLOCKS, 256, 0, stream>>>(off, partial, N_NODES);
  scan_partials_kernel<<<1, 256, 0, stream>>>(partial, off, SCAN_BLOCKS, N_NODES);
  scan_apply_kernel<<<SCAN_BLOCKS, 256, 0, stream>>>(partial, off, cursor, N_NODES);
  scatter_kernel<<<(N_EDGES + 255) / 256, 256, 0, stream>>>(edst, cursor, eids, N_EDGES);

  // conv1
  agg_z_kernel<<<4096, 256, 0, stream>>>(bufA, off, eids, esrc, eattr, We1, be1, eps1, bufZ);
  mlp_kernel<<<3125, 256, 0, stream>>>(bufZ, 1, Wt11, b11, Wt12, b12, 1, bufA);
  // conv2
  agg_z_kernel<<<4096, 256, 0, stream>>>(bufA, off, eids, esrc, eattr, We2, be2, eps2, bufZ);
  mlp_kernel<<<3125, 256, 0, stream>>>(bufZ, 1, Wt21, b21, Wt22, b22, 1, (float*)d_out);
}

// Round 3
// 562.976 us; speedup vs baseline: 1.6243x; 1.1720x over previous
//
#include <hip/hip_runtime.h>
#include <stdint.h>

#define N_NODES 200000
#define N_EDGES 600000
#define SCAN_CHUNK 1024
#define SCAN_BLOCKS ((N_NODES + SCAN_CHUNK - 1) / SCAN_CHUNK)  // 196

typedef __attribute__((ext_vector_type(8))) short short8;
typedef __attribute__((ext_vector_type(4))) float floatx4;
typedef __attribute__((ext_vector_type(2))) float floatx2;

static __device__ __forceinline__ unsigned short f2bf(float f) {
  union { float f; unsigned u; } c; c.f = f;
  unsigned u = c.u;
  unsigned r = (u + 0x7fffu + ((u >> 16) & 1u)) >> 16;
  return (unsigned short)r;
}
static __device__ __forceinline__ float asf(unsigned u) {
  union { unsigned u; float f; } c; c.u = u; return c.f;
}

// ---------------- weight prep: f32 [128][128] -> bf16 transposed [n][k] ----------------
__global__ __launch_bounds__(256) void prep_kernel(
    const float* w0, const float* w1, const float* w2, const float* w3, const float* w4,
    unsigned short* out) {
  const float* src;
  switch (blockIdx.y) {
    case 0: src = w0; break;
    case 1: src = w1; break;
    case 2: src = w2; break;
    case 3: src = w3; break;
    default: src = w4; break;
  }
  unsigned short* dst = out + (size_t)blockIdx.y * 16384;
  int t = blockIdx.x * 256 + threadIdx.x;  // 0..4095
#pragma unroll
  for (int i = 0; i < 4; ++i) {
    int idx = t + 4096 * i;  // idx = n*128 + k
    int n = idx >> 7, k = idx & 127;
    dst[idx] = f2bf(src[k * 128 + n]);
  }
}

// ---------------- CSR build ----------------
__global__ __launch_bounds__(256) void hist_kernel(const int* __restrict__ dst, int* deg, int E) {
  int e = blockIdx.x * 256 + threadIdx.x;
  if (e < E) atomicAdd(&deg[dst[e]], 1);
}

// pass 1: per-block partial sums of deg
__global__ __launch_bounds__(256) void scan_sum_kernel(const int* __restrict__ deg, int* partial,
                                                       int n) {
  __shared__ int wsum[4];
  const int tid = threadIdx.x, lane = tid & 63, wid = tid >> 6;
  int idx0 = blockIdx.x * SCAN_CHUNK + tid * 4;
  int s = 0;
#pragma unroll
  for (int j = 0; j < 4; ++j) {
    int ix = idx0 + j;
    if (ix < n) s += deg[ix];
  }
#pragma unroll
  for (int d = 32; d >= 1; d >>= 1) s += __shfl_down(s, d, 64);
  if (lane == 0) wsum[wid] = s;
  __syncthreads();
  if (tid == 0) partial[blockIdx.x] = wsum[0] + wsum[1] + wsum[2] + wsum[3];
}

// pass 2: single-block exclusive scan of partials (nb <= 256), writes off[n]=total
__global__ __launch_bounds__(256) void scan_partials_kernel(int* partial, int* off, int nb, int n) {
  __shared__ int wsum[4];
  const int tid = threadIdx.x, lane = tid & 63, wid = tid >> 6;
  int val = (tid < nb) ? partial[tid] : 0;
  int incl = val;
#pragma unroll
  for (int d = 1; d < 64; d <<= 1) {
    int t = __shfl_up(incl, d, 64);
    if (lane >= d) incl += t;
  }
  if (lane == 63) wsum[wid] = incl;
  __syncthreads();
  int base = 0;
  for (int w = 0; w < wid; ++w) base += wsum[w];
  int excl = base + incl - val;
  if (tid < nb) partial[tid] = excl;
  if (tid == 0) off[n] = wsum[0] + wsum[1] + wsum[2] + wsum[3];
}

// pass 3: per-block local exclusive scan + block base; writes off[] and cursor[]
__global__ __launch_bounds__(256) void scan_apply_kernel(const int* __restrict__ partial, int* off,
                                                         int* cursor, int n) {
  __shared__ int wsum[4];
  const int tid = threadIdx.x, lane = tid & 63, wid = tid >> 6;
  int idx0 = blockIdx.x * SCAN_CHUNK + tid * 4;
  int v[4];
  int s = 0;
#pragma unroll
  for (int j = 0; j < 4; ++j) {
    int ix = idx0 + j;
    v[j] = (ix < n) ? off[ix] : 0;
    s += v[j];
  }
  int incl = s;
#pragma unroll
  for (int d = 1; d < 64; d <<= 1) {
    int t = __shfl_up(incl, d, 64);
    if (lane >= d) incl += t;
  }
  if (lane == 63) wsum[wid] = incl;
  __syncthreads();
  int base = partial[blockIdx.x];
  for (int w = 0; w < wid; ++w) base += wsum[w];
  int running = base + incl - s;
#pragma unroll
  for (int j = 0; j < 4; ++j) {
    int ix = idx0 + j;
    if (ix < n) { off[ix] = running; cursor[ix] = running; }
    running += v[j];
  }
}

// scatter edge ids AND source node ids into CSR order
__global__ __launch_bounds__(256) void scatter_kernel(const int* __restrict__ dst,
                                                      const int* __restrict__ src, int* cursor,
                                                      int* eids, int* srcs, int E) {
  int e = blockIdx.x * 256 + threadIdx.x;
  if (e < E) {
    int p = atomicAdd(&cursor[dst[e]], 1);
    eids[p] = e;
    srcs[p] = src[e];
  }
}

// ---------------- aggregation + z = (1+eps)*h + sum relu(h[src]+ef) ----------------
// one wave per node; lane handles channels (2*lane, 2*lane+1); We kept in registers.
// h stored bf16; edge list batch-loaded lane-parallel, broadcast via readlane (SGPR).
__global__ __launch_bounds__(256) void agg_z_kernel(
    const unsigned short* __restrict__ hB, const int* __restrict__ off,
    const int* __restrict__ eids, const int* __restrict__ srcs,
    const float* __restrict__ edge_attr,
    const float* __restrict__ We, const float* __restrict__ be,
    const float* __restrict__ epsPtr, unsigned short* __restrict__ z) {
  const int lane = threadIdx.x & 63;
  const int wv = threadIdx.x >> 6;
  const int c = lane * 2;
  floatx2 wr[16];
#pragma unroll
  for (int d = 0; d < 16; ++d) {
    float2 t = *((const float2*)(We + d * 128 + c));
    wr[d].x = t.x; wr[d].y = t.y;
  }
  const float2 bev = *((const float2*)(be + c));
  const float epsp = 1.0f + epsPtr[0];
  const int waveId = blockIdx.x * 4 + wv;
  const int nWaves = gridDim.x * 4;
  for (int node = waveId; node < N_NODES; node += nWaves) {
    floatx2 acc; acc.x = 0.0f; acc.y = 0.0f;
    const int s0 = off[node], s1 = off[node + 1];
    for (int base = s0; base < s1; base += 64) {
      int nrem = s1 - base; if (nrem > 64) nrem = 64;
      int e_l = 0, sn_l = 0;
      if (base + lane < s1) {
        e_l = eids[base + lane];
        sn_l = srcs[base + lane];
      }
      for (int j = 0; j < nrem; ++j) {
        const int e = __builtin_amdgcn_readlane(e_l, j);
        const int sn = __builtin_amdgcn_readlane(sn_l, j);
        const unsigned hw = *((const unsigned*)(hB + (size_t)sn * 128 + c));
        const float4 q0 = *((const float4*)(edge_attr + (size_t)e * 16));
        const float4 q1 = *((const float4*)(edge_attr + (size_t)e * 16 + 4));
        const float4 q2 = *((const float4*)(edge_attr + (size_t)e * 16 + 8));
        const float4 q3 = *((const float4*)(edge_attr + (size_t)e * 16 + 12));
        floatx2 ef; ef.x = bev.x; ef.y = bev.y;
        ef += q0.x * wr[0];
        ef += q0.y * wr[1];
        ef += q0.z * wr[2];
        ef += q0.w * wr[3];
        ef += q1.x * wr[4];
        ef += q1.y * wr[5];
        ef += q1.z * wr[6];
        ef += q1.w * wr[7];
        ef += q2.x * wr[8];
        ef += q2.y * wr[9];
        ef += q2.z * wr[10];
        ef += q2.w * wr[11];
        ef += q3.x * wr[12];
        ef += q3.y * wr[13];
        ef += q3.z * wr[14];
        ef += q3.w * wr[15];
        floatx2 hv;
        hv.x = asf(hw << 16);
        hv.y = asf(hw & 0xffff0000u);
        floatx2 m = ef + hv;
        m.x = fmaxf(m.x, 0.0f);
        m.y = fmaxf(m.y, 0.0f);
        acc += m;
      }
    }
    const unsigned hw = *((const unsigned*)(hB + (size_t)node * 128 + c));
    const float hx = asf(hw << 16);
    const float hy = asf(hw & 0xffff0000u);
    unsigned p = (unsigned)f2bf(fmaf(epsp, hx, acc.x)) |
                 ((unsigned)f2bf(fmaf(epsp, hy, acc.y)) << 16);
    *((unsigned*)(z + (size_t)node * 128 + c)) = p;
  }
}

// ---------------- fused (1 or 2)-layer MLP GEMM, M-tile=64, N=K=128, bf16 MFMA ----------------
__global__ __launch_bounds__(256) void mlp_kernel(
    const void* __restrict__ Ain, int aIsBf16,
    const unsigned short* __restrict__ W1t, const float* __restrict__ b1,
    const unsigned short* __restrict__ W2t, const float* __restrict__ b2,
    int twoStage, int outBf16, void* __restrict__ out) {
  __shared__ unsigned short sA[64][136];
  __shared__ unsigned short sW[128][136];
  const int tid = threadIdx.x;
  const int lane = tid & 63;
  const int wv = tid >> 6;
  const int lr = lane & 15, quad = lane >> 4;
  const int mw = wv >> 1, nw = wv & 1;
  const size_t rowBase = (size_t)blockIdx.x * 64;

  if (aIsBf16) {
    const uint4* src = (const uint4*)((const unsigned short*)Ain + rowBase * 128);
#pragma unroll
    for (int i = 0; i < 4; ++i) {
      int idx = tid + 256 * i;  // 0..1023 chunks of 8 bf16
      int r = idx >> 4, c8 = idx & 15;
      uint4 v = src[idx];
      *((uint4*)&sA[r][c8 * 8]) = v;
    }
  } else {
    const float4* src = (const float4*)((const float*)Ain + rowBase * 128);
#pragma unroll
    for (int i = 0; i < 8; ++i) {
      int idx = tid + 256 * i;  // 0..2047 float4
      int r = idx >> 5, c4 = idx & 31;
      float4 v = src[idx];
      uint2 p;
      p.x = (unsigned)f2bf(v.x) | ((unsigned)f2bf(v.y) << 16);
      p.y = (unsigned)f2bf(v.z) | ((unsigned)f2bf(v.w) << 16);
      *((uint2*)&sA[r][c4 * 4]) = p;
    }
  }
  {
    const uint4* srcw = (const uint4*)W1t;
#pragma unroll
    for (int i = 0; i < 8; ++i) {
      int idx = tid + 256 * i;  // 0..2047 chunks of 8 bf16
      int r = idx >> 4, c8 = idx & 15;
      *((uint4*)&sW[r][c8 * 8]) = srcw[idx];
    }
  }
  __syncthreads();

  floatx4 acc[2][4];
#pragma unroll
  for (int mi = 0; mi < 2; ++mi)
#pragma unroll
    for (int ni = 0; ni < 4; ++ni)
#pragma unroll
      for (int i = 0; i < 4; ++i) acc[mi][ni][i] = 0.0f;

#pragma unroll
  for (int kk = 0; kk < 4; ++kk) {
    short8 a[2], b[4];
#pragma unroll
    for (int mi = 0; mi < 2; ++mi)
      a[mi] = *((const short8*)&sA[32 * mw + 16 * mi + lr][kk * 32 + quad * 8]);
#pragma unroll
    for (int ni = 0; ni < 4; ++ni)
      b[ni] = *((const short8*)&sW[64 * nw + 16 * ni + lr][kk * 32 + quad * 8]);
#pragma unroll
    for (int mi = 0; mi < 2; ++mi)
#pragma unroll
      for (int ni = 0; ni < 4; ++ni)
        acc[mi][ni] = __builtin_amdgcn_mfma_f32_16x16x32_bf16(a[mi], b[ni], acc[mi][ni], 0, 0, 0);
  }

  if (!twoStage) {
#pragma unroll
    for (int mi = 0; mi < 2; ++mi)
#pragma unroll
      for (int ni = 0; ni < 4; ++ni)
#pragma unroll
        for (int i = 0; i < 4; ++i) {
          int row = 32 * mw + 16 * mi + quad * 4 + i;
          int col = 64 * nw + 16 * ni + lr;
          float v = fmaxf(acc[mi][ni][i] + b1[col], 0.0f);
          if (outBf16)
            ((unsigned short*)out)[(rowBase + row) * 128 + col] = f2bf(v);
          else
            ((float*)out)[(rowBase + row) * 128 + col] = v;
        }
    return;
  }

  __syncthreads();  // all stage-1 LDS reads done
  // write t = relu(z@W1+b1) into sA as bf16
#pragma unroll
  for (int mi = 0; mi < 2; ++mi)
#pragma unroll
    for (int ni = 0; ni < 4; ++ni)
#pragma unroll
      for (int i = 0; i < 4; ++i) {
        int row = 32 * mw + 16 * mi + quad * 4 + i;
        int col = 64 * nw + 16 * ni + lr;
        sA[row][col] = f2bf(fmaxf(acc[mi][ni][i] + b1[col], 0.0f));
      }
  // reload W2t
  {
    const uint4* srcw = (const uint4*)W2t;
#pragma unroll
    for (int i = 0; i < 8; ++i) {
      int idx = tid + 256 * i;
      int r = idx >> 4, c8 = idx & 15;
      *((uint4*)&sW[r][c8 * 8]) = srcw[idx];
    }
  }
  __syncthreads();

  floatx4 acc2[2][4];
#pragma unroll
  for (int mi = 0; mi < 2; ++mi)
#pragma unroll
    for (int ni = 0; ni < 4; ++ni)
#pragma unroll
      for (int i = 0; i < 4; ++i) acc2[mi][ni][i] = 0.0f;

#pragma unroll
  for (int kk = 0; kk < 4; ++kk) {
    short8 a[2], b[4];
#pragma unroll
    for (int mi = 0; mi < 2; ++mi)
      a[mi] = *((const short8*)&sA[32 * mw + 16 * mi + lr][kk * 32 + quad * 8]);
#pragma unroll
    for (int ni = 0; ni < 4; ++ni)
      b[ni] = *((const short8*)&sW[64 * nw + 16 * ni + lr][kk * 32 + quad * 8]);
#pragma unroll
    for (int mi = 0; mi < 2; ++mi)
#pragma unroll
      for (int ni = 0; ni < 4; ++ni)
        acc2[mi][ni] = __builtin_amdgcn_mfma_f32_16x16x32_bf16(a[mi], b[ni], acc2[mi][ni], 0, 0, 0);
  }

#pragma unroll
  for (int mi = 0; mi < 2; ++mi)
#pragma unroll
    for (int ni = 0; ni < 4; ++ni)
#pragma unroll
      for (int i = 0; i < 4; ++i) {
        int row = 32 * mw + 16 * mi + quad * 4 + i;
        int col = 64 * nw + 16 * ni + lr;
        float v = fmaxf(acc2[mi][ni][i] + b2[col], 0.0f);
        if (outBf16)
          ((unsigned short*)out)[(rowBase + row) * 128 + col] = f2bf(v);
        else
          ((float*)out)[(rowBase + row) * 128 + col] = v;
      }
}

extern "C" void kernel_launch(void* const* d_in, const int* in_sizes, int n_in,
                              void* d_out, int out_size, void* d_ws, size_t ws_size,
                              hipStream_t stream) {
  (void)in_sizes; (void)n_in; (void)out_size; (void)ws_size;
  const float* x = (const float*)d_in[0];
  const int* eidx = (const int*)d_in[1];
  const int* esrc = eidx;
  const int* edst = eidx + N_EDGES;
  const float* eattr = (const float*)d_in[2];
  const float* W_enc = (const float*)d_in[3];
  const float* b_enc = (const float*)d_in[4];
  const float* We1 = (const float*)d_in[5];
  const float* be1 = (const float*)d_in[6];
  const float* W11 = (const float*)d_in[7];
  const float* b11 = (const float*)d_in[8];
  const float* W12 = (const float*)d_in[9];
  const float* b12 = (const float*)d_in[10];
  const float* eps1 = (const float*)d_in[11];
  const float* We2 = (const float*)d_in[12];
  const float* be2 = (const float*)d_in[13];
  const float* W21 = (const float*)d_in[14];
  const float* b21 = (const float*)d_in[15];
  const float* W22 = (const float*)d_in[16];
  const float* b22 = (const float*)d_in[17];
  const float* eps2 = (const float*)d_in[18];

  char* ws = (char*)d_ws;
  unsigned short* wt = (unsigned short*)ws;                                   // 163840 B
  unsigned short* hB = (unsigned short*)(ws + 163840);                        // 51,200,000 B
  unsigned short* bufZ = (unsigned short*)(ws + 163840 + 51200000ull);        // 51,200,000 B
  int* off = (int*)(ws + 163840 + 2ull * 51200000ull);                        // (N+1)*4
  int* cursor = off + (N_NODES + 1);
  int* eids = cursor + N_NODES;
  int* srcs = eids + N_EDGES;
  int* partial = srcs + N_EDGES;  // SCAN_BLOCKS ints

  unsigned short* Wt_enc = wt;
  unsigned short* Wt11 = wt + 16384;
  unsigned short* Wt12 = wt + 2 * 16384;
  unsigned short* Wt21 = wt + 3 * 16384;
  unsigned short* Wt22 = wt + 4 * 16384;

  hipMemsetAsync(off, 0, (N_NODES + 1) * sizeof(int), stream);
  prep_kernel<<<dim3(16, 5), 256, 0, stream>>>(W_enc, W11, W12, W21, W22, wt);

  // h0 = relu(x @ W_enc + b_enc) -> bf16
  mlp_kernel<<<3125, 256, 0, stream>>>(x, 0, Wt_enc, b_enc, Wt_enc, b_enc, 0, 1, hB);

  hist_kernel<<<(N_EDGES + 255) / 256, 256, 0, stream>>>(edst, off, N_EDGES);
  scan_sum_kernel<<<SCAN_BLOCKS, 256, 0, stream>>>(off, partial, N_NODES);
  scan_partials_kernel<<<1, 256, 0, stream>>>(partial, off, SCAN_BLOCKS, N_NODES);
  scan_apply_kernel<<<SCAN_BLOCKS, 256, 0, stream>>>(partial, off, cursor, N_NODES);
  scatter_kernel<<<(N_EDGES + 255) / 256, 256, 0, stream>>>(edst, esrc, cursor, eids, srcs,
                                                            N_EDGES);

  // conv1
  agg_z_kernel<<<4096, 256, 0, stream>>>(hB, off, eids, srcs, eattr, We1, be1, eps1, bufZ);
  mlp_kernel<<<3125, 256, 0, stream>>>(bufZ, 1, Wt11, b11, Wt12, b12, 1, 1, hB);
  // conv2
  agg_z_kernel<<<4096, 256, 0, stream>>>(hB, off, eids, srcs, eattr, We2, be2, eps2, bufZ);
  mlp_kernel<<<3125, 256, 0, stream>>>(bufZ, 1, Wt21, b21, Wt22, b22, 1, 0, d_out);
}

// Round 4
// 516.559 us; speedup vs baseline: 1.7702x; 1.0899x over previous
//
#include <hip/hip_runtime.h>
#include <stdint.h>

#define N_NODES 200000
#define N_EDGES 600000
#define SCAN_CHUNK 1024
#define SCAN_BLOCKS ((N_NODES + SCAN_CHUNK - 1) / SCAN_CHUNK)  // 196
#define GRID_AGG 4096
#define NWAVES (GRID_AGG * 4)  // 16384 waves, ~36.6 edges each

typedef __attribute__((ext_vector_type(8))) short short8;
typedef __attribute__((ext_vector_type(4))) float floatx4;
typedef __attribute__((ext_vector_type(2))) float floatx2;

static __device__ __forceinline__ unsigned short f2bf(float f) {
  union { float f; unsigned u; } c; c.f = f;
  unsigned u = c.u;
  unsigned r = (u + 0x7fffu + ((u >> 16) & 1u)) >> 16;
  return (unsigned short)r;
}
static __device__ __forceinline__ float asf(unsigned u) {
  union { unsigned u; float f; } c; c.u = u; return c.f;
}

// ---------------- weight prep: f32 [128][128] -> bf16 transposed [n][k] ----------------
__global__ __launch_bounds__(256) void prep_kernel(
    const float* w0, const float* w1, const float* w2, const float* w3, const float* w4,
    unsigned short* out) {
  const float* src;
  switch (blockIdx.y) {
    case 0: src = w0; break;
    case 1: src = w1; break;
    case 2: src = w2; break;
    case 3: src = w3; break;
    default: src = w4; break;
  }
  unsigned short* dst = out + (size_t)blockIdx.y * 16384;
  int t = blockIdx.x * 256 + threadIdx.x;  // 0..4095
#pragma unroll
  for (int i = 0; i < 4; ++i) {
    int idx = t + 4096 * i;  // idx = n*128 + k
    int n = idx >> 7, k = idx & 127;
    dst[idx] = f2bf(src[k * 128 + n]);
  }
}

// ---------------- CSR build ----------------
__global__ __launch_bounds__(256) void hist_kernel(const int* __restrict__ dst, int* deg, int E) {
  int e = blockIdx.x * 256 + threadIdx.x;
  if (e < E) atomicAdd(&deg[dst[e]], 1);
}

// pass 1: per-block partial sums of deg
__global__ __launch_bounds__(256) void scan_sum_kernel(const int* __restrict__ deg, int* partial,
                                                       int n) {
  __shared__ int wsum[4];
  const int tid = threadIdx.x, lane = tid & 63, wid = tid >> 6;
  int idx0 = blockIdx.x * SCAN_CHUNK + tid * 4;
  int s = 0;
#pragma unroll
  for (int j = 0; j < 4; ++j) {
    int ix = idx0 + j;
    if (ix < n) s += deg[ix];
  }
#pragma unroll
  for (int d = 32; d >= 1; d >>= 1) s += __shfl_down(s, d, 64);
  if (lane == 0) wsum[wid] = s;
  __syncthreads();
  if (tid == 0) partial[blockIdx.x] = wsum[0] + wsum[1] + wsum[2] + wsum[3];
}

// pass 2: single-block exclusive scan of partials (nb <= 256), writes off[n]=total
__global__ __launch_bounds__(256) void scan_partials_kernel(int* partial, int* off, int nb, int n) {
  __shared__ int wsum[4];
  const int tid = threadIdx.x, lane = tid & 63, wid = tid >> 6;
  int val = (tid < nb) ? partial[tid] : 0;
  int incl = val;
#pragma unroll
  for (int d = 1; d < 64; d <<= 1) {
    int t = __shfl_up(incl, d, 64);
    if (lane >= d) incl += t;
  }
  if (lane == 63) wsum[wid] = incl;
  __syncthreads();
  int base = 0;
  for (int w = 0; w < wid; ++w) base += wsum[w];
  int excl = base + incl - val;
  if (tid < nb) partial[tid] = excl;
  if (tid == 0) off[n] = wsum[0] + wsum[1] + wsum[2] + wsum[3];
}

// pass 3: per-block local exclusive scan + block base; writes off[] and cursor[]
__global__ __launch_bounds__(256) void scan_apply_kernel(const int* __restrict__ partial, int* off,
                                                         int* cursor, int n) {
  __shared__ int wsum[4];
  const int tid = threadIdx.x, lane = tid & 63, wid = tid >> 6;
  int idx0 = blockIdx.x * SCAN_CHUNK + tid * 4;
  int v[4];
  int s = 0;
#pragma unroll
  for (int j = 0; j < 4; ++j) {
    int ix = idx0 + j;
    v[j] = (ix < n) ? off[ix] : 0;
    s += v[j];
  }
  int incl = s;
#pragma unroll
  for (int d = 1; d < 64; d <<= 1) {
    int t = __shfl_up(incl, d, 64);
    if (lane >= d) incl += t;
  }
  if (lane == 63) wsum[wid] = incl;
  __syncthreads();
  int base = partial[blockIdx.x];
  for (int w = 0; w < wid; ++w) base += wsum[w];
  int running = base + incl - s;
#pragma unroll
  for (int j = 0; j < 4; ++j) {
    int ix = idx0 + j;
    if (ix < n) { off[ix] = running; cursor[ix] = running; }
    running += v[j];
  }
}

// scatter src node ids AND edge_attr rows into CSR (dst-sorted) order
__global__ __launch_bounds__(256) void scatter_kernel(const int* __restrict__ dst,
                                                      const int* __restrict__ src,
                                                      const float* __restrict__ eattr, int* cursor,
                                                      int* srcs, float* eaC, int E) {
  int e = blockIdx.x * 256 + threadIdx.x;
  if (e < E) {
    int p = atomicAdd(&cursor[dst[e]], 1);
    srcs[p] = src[e];
    const float4* q = (const float4*)(eattr + (size_t)e * 16);
    float4* o = (float4*)(eaC + (size_t)p * 16);
    o[0] = q[0]; o[1] = q[1]; o[2] = q[2]; o[3] = q[3];
  }
}

// wave w handles nodes [waveStart[w], waveStart[w+1]): balanced-by-edges contiguous ranges
__global__ __launch_bounds__(256) void partition_kernel(const int* __restrict__ off,
                                                        int* waveStart) {
  int w = blockIdx.x * 256 + threadIdx.x;
  if (w > NWAVES) return;
  if (w == NWAVES) { waveStart[w] = N_NODES; return; }
  long long t = (long long)w * N_EDGES / NWAVES;
  int lo = 0, hi = N_NODES;
  while (lo < hi) {
    int mid = (lo + hi) >> 1;
    if (off[mid] < (int)t) lo = mid + 1; else hi = mid;
  }
  waveStart[w] = lo;
}

// ---------------- aggregation + z = (1+eps)*h + sum relu(h[src]+ef) ----------------
// one wave per balanced node-range; lane covers channels (2*lane, 2*lane+1).
// off boundaries + srcs batch-loaded lane-parallel once; per node all gathers issued together.
__global__ __launch_bounds__(256) void agg_z_kernel(
    const unsigned short* __restrict__ hB, const int* __restrict__ off,
    const int* __restrict__ waveStart, const int* __restrict__ srcs,
    const float* __restrict__ eaC,
    const float* __restrict__ We, const float* __restrict__ be,
    const float* __restrict__ epsPtr, unsigned short* __restrict__ z) {
  const int lane = threadIdx.x & 63;
  const int wv = threadIdx.x >> 6;
  const int c = lane * 2;
  floatx2 wr[16];
#pragma unroll
  for (int d = 0; d < 16; ++d) {
    float2 t = *((const float2*)(We + d * 128 + c));
    wr[d].x = t.x; wr[d].y = t.y;
  }
  const float2 bev = *((const float2*)(be + c));
  const float epsp = 1.0f + epsPtr[0];
  const int w = blockIdx.x * 4 + wv;
  const int n0 = waveStart[w];
  const int n1 = waveStart[w + 1];
  if (n0 >= n1) return;

  int obase = n0;
  {
    int ix = obase + lane; if (ix > n1) ix = n1;
  }
  int ix0 = obase + lane; if (ix0 > n1) ix0 = n1;
  int offv = off[ix0];
  int ii = __builtin_amdgcn_readlane(offv, 0);
  int ebase = ii;
  int sx0 = ebase + lane; if (sx0 > N_EDGES - 1) sx0 = N_EDGES - 1;
  int sbuf = srcs[sx0];

#define EDGE_COMPUTE(EIDX, HW) { \
    const float* ea = eaC + (size_t)(EIDX) * 16; \
    const float4 q0 = *((const float4*)(ea)); \
    const float4 q1 = *((const float4*)(ea + 4)); \
    const float4 q2 = *((const float4*)(ea + 8)); \
    const float4 q3 = *((const float4*)(ea + 12)); \
    floatx2 efa; efa.x = bev.x; efa.y = bev.y; \
    floatx2 efb; efb.x = 0.0f; efb.y = 0.0f; \
    efa += q0.x * wr[0]; efb += q0.y * wr[1]; \
    efa += q0.z * wr[2]; efb += q0.w * wr[3]; \
    efa += q1.x * wr[4]; efb += q1.y * wr[5]; \
    efa += q1.z * wr[6]; efb += q1.w * wr[7]; \
    efa += q2.x * wr[8]; efb += q2.y * wr[9]; \
    efa += q2.z * wr[10]; efb += q2.w * wr[11]; \
    efa += q3.x * wr[12]; efb += q3.y * wr[13]; \
    efa += q3.z * wr[14]; efb += q3.w * wr[15]; \
    floatx2 hv; hv.x = asf((HW) << 16); hv.y = asf((HW) & 0xffff0000u); \
    floatx2 mm = (efa + efb) + hv; \
    mm.x = fmaxf(mm.x, 0.0f); mm.y = fmaxf(mm.y, 0.0f); \
    acc += mm; }

  for (int n = n0; n < n1; ++n) {
    if (n + 1 - obase >= 64) {
      obase = n;
      int ix = obase + lane; if (ix > n1) ix = n1;
      offv = off[ix];
    }
    const int eE = __builtin_amdgcn_readlane(offv, n + 1 - obase);
    const unsigned hwn = *((const unsigned*)(hB + (size_t)n * 128 + c));
    floatx2 acc; acc.x = 0.0f; acc.y = 0.0f;
    while (ii < eE) {
      int m = eE - ii; if (m > 4) m = 4;
      if (ii + m > ebase + 64) {
        ebase = ii;
        int sx = ebase + lane; if (sx > N_EDGES - 1) sx = N_EDGES - 1;
        sbuf = srcs[sx];
      }
      const int j = ii - ebase;
      const int sn0 = __builtin_amdgcn_readlane(sbuf, j);
      const int sn1_ = __builtin_amdgcn_readlane(sbuf, (j + 1) & 63);
      const int sn2_ = __builtin_amdgcn_readlane(sbuf, (j + 2) & 63);
      const int sn3_ = __builtin_amdgcn_readlane(sbuf, (j + 3) & 63);
      unsigned hw0, hw1 = 0, hw2 = 0, hw3 = 0;
      hw0 = *((const unsigned*)(hB + (size_t)sn0 * 128 + c));
      if (m > 1) hw1 = *((const unsigned*)(hB + (size_t)sn1_ * 128 + c));
      if (m > 2) hw2 = *((const unsigned*)(hB + (size_t)sn2_ * 128 + c));
      if (m > 3) hw3 = *((const unsigned*)(hB + (size_t)sn3_ * 128 + c));
      EDGE_COMPUTE(ii, hw0);
      if (m > 1) EDGE_COMPUTE(ii + 1, hw1);
      if (m > 2) EDGE_COMPUTE(ii + 2, hw2);
      if (m > 3) EDGE_COMPUTE(ii + 3, hw3);
      ii += m;
    }
    const float hx = asf(hwn << 16);
    const float hy = asf(hwn & 0xffff0000u);
    unsigned p = (unsigned)f2bf(fmaf(epsp, hx, acc.x)) |
                 ((unsigned)f2bf(fmaf(epsp, hy, acc.y)) << 16);
    *((unsigned*)(z + (size_t)n * 128 + c)) = p;
  }
#undef EDGE_COMPUTE
}

// ---------------- fused (1 or 2)-layer MLP GEMM, M-tile=64, N=K=128, bf16 MFMA ----------------
__global__ __launch_bounds__(256) void mlp_kernel(
    const void* __restrict__ Ain, int aIsBf16,
    const unsigned short* __restrict__ W1t, const float* __restrict__ b1,
    const unsigned short* __restrict__ W2t, const float* __restrict__ b2,
    int twoStage, int outBf16, void* __restrict__ out) {
  __shared__ unsigned short sA[64][136];
  __shared__ unsigned short sW[128][136];
  const int tid = threadIdx.x;
  const int lane = tid & 63;
  const int wv = tid >> 6;
  const int lr = lane & 15, quad = lane >> 4;
  const int mw = wv >> 1, nw = wv & 1;
  const size_t rowBase = (size_t)blockIdx.x * 64;

  if (aIsBf16) {
    const uint4* src = (const uint4*)((const unsigned short*)Ain + rowBase * 128);
#pragma unroll
    for (int i = 0; i < 4; ++i) {
      int idx = tid + 256 * i;  // 0..1023 chunks of 8 bf16
      int r = idx >> 4, c8 = idx & 15;
      uint4 v = src[idx];
      *((uint4*)&sA[r][c8 * 8]) = v;
    }
  } else {
    const float4* src = (const float4*)((const float*)Ain + rowBase * 128);
#pragma unroll
    for (int i = 0; i < 8; ++i) {
      int idx = tid + 256 * i;  // 0..2047 float4
      int r = idx >> 5, c4 = idx & 31;
      float4 v = src[idx];
      uint2 p;
      p.x = (unsigned)f2bf(v.x) | ((unsigned)f2bf(v.y) << 16);
      p.y = (unsigned)f2bf(v.z) | ((unsigned)f2bf(v.w) << 16);
      *((uint2*)&sA[r][c4 * 4]) = p;
    }
  }
  {
    const uint4* srcw = (const uint4*)W1t;
#pragma unroll
    for (int i = 0; i < 8; ++i) {
      int idx = tid + 256 * i;  // 0..2047 chunks of 8 bf16
      int r = idx >> 4, c8 = idx & 15;
      *((uint4*)&sW[r][c8 * 8]) = srcw[idx];
    }
  }
  __syncthreads();

  floatx4 acc[2][4];
#pragma unroll
  for (int mi = 0; mi < 2; ++mi)
#pragma unroll
    for (int ni = 0; ni < 4; ++ni)
#pragma unroll
      for (int i = 0; i < 4; ++i) acc[mi][ni][i] = 0.0f;

#pragma unroll
  for (int kk = 0; kk < 4; ++kk) {
    short8 a[2], b[4];
#pragma unroll
    for (int mi = 0; mi < 2; ++mi)
      a[mi] = *((const short8*)&sA[32 * mw + 16 * mi + lr][kk * 32 + quad * 8]);
#pragma unroll
    for (int ni = 0; ni < 4; ++ni)
      b[ni] = *((const short8*)&sW[64 * nw + 16 * ni + lr][kk * 32 + quad * 8]);
#pragma unroll
    for (int mi = 0; mi < 2; ++mi)
#pragma unroll
      for (int ni = 0; ni < 4; ++ni)
        acc[mi][ni] = __builtin_amdgcn_mfma_f32_16x16x32_bf16(a[mi], b[ni], acc[mi][ni], 0, 0, 0);
  }

  if (!twoStage) {
#pragma unroll
    for (int mi = 0; mi < 2; ++mi)
#pragma unroll
      for (int ni = 0; ni < 4; ++ni)
#pragma unroll
        for (int i = 0; i < 4; ++i) {
          int row = 32 * mw + 16 * mi + quad * 4 + i;
          int col = 64 * nw + 16 * ni + lr;
          float v = fmaxf(acc[mi][ni][i] + b1[col], 0.0f);
          if (outBf16)
            ((unsigned short*)out)[(rowBase + row) * 128 + col] = f2bf(v);
          else
            ((float*)out)[(rowBase + row) * 128 + col] = v;
        }
    return;
  }

  __syncthreads();  // all stage-1 LDS reads done
  // write t = relu(z@W1+b1) into sA as bf16
#pragma unroll
  for (int mi = 0; mi < 2; ++mi)
#pragma unroll
    for (int ni = 0; ni < 4; ++ni)
#pragma unroll
      for (int i = 0; i < 4; ++i) {
        int row = 32 * mw + 16 * mi + quad * 4 + i;
        int col = 64 * nw + 16 * ni + lr;
        sA[row][col] = f2bf(fmaxf(acc[mi][ni][i] + b1[col], 0.0f));
      }
  // reload W2t
  {
    const uint4* srcw = (const uint4*)W2t;
#pragma unroll
    for (int i = 0; i < 8; ++i) {
      int idx = tid + 256 * i;
      int r = idx >> 4, c8 = idx & 15;
      *((uint4*)&sW[r][c8 * 8]) = srcw[idx];
    }
  }
  __syncthreads();

  floatx4 acc2[2][4];
#pragma unroll
  for (int mi = 0; mi < 2; ++mi)
#pragma unroll
    for (int ni = 0; ni < 4; ++ni)
#pragma unroll
      for (int i = 0; i < 4; ++i) acc2[mi][ni][i] = 0.0f;

#pragma unroll
  for (int kk = 0; kk < 4; ++kk) {
    short8 a[2], b[4];
#pragma unroll
    for (int mi = 0; mi < 2; ++mi)
      a[mi] = *((const short8*)&sA[32 * mw + 16 * mi + lr][kk * 32 + quad * 8]);
#pragma unroll
    for (int ni = 0; ni < 4; ++ni)
      b[ni] = *((const short8*)&sW[64 * nw + 16 * ni + lr][kk * 32 + quad * 8]);
#pragma unroll
    for (int mi = 0; mi < 2; ++mi)
#pragma unroll
      for (int ni = 0; ni < 4; ++ni)
        acc2[mi][ni] = __builtin_amdgcn_mfma_f32_16x16x32_bf16(a[mi], b[ni], acc2[mi][ni], 0, 0, 0);
  }

#pragma unroll
  for (int mi = 0; mi < 2; ++mi)
#pragma unroll
    for (int ni = 0; ni < 4; ++ni)
#pragma unroll
      for (int i = 0; i < 4; ++i) {
        int row = 32 * mw + 16 * mi + quad * 4 + i;
        int col = 64 * nw + 16 * ni + lr;
        float v = fmaxf(acc2[mi][ni][i] + b2[col], 0.0f);
        if (outBf16)
          ((unsigned short*)out)[(rowBase + row) * 128 + col] = f2bf(v);
        else
          ((float*)out)[(rowBase + row) * 128 + col] = v;
      }
}

extern "C" void kernel_launch(void* const* d_in, const int* in_sizes, int n_in,
                              void* d_out, int out_size, void* d_ws, size_t ws_size,
                              hipStream_t stream) {
  (void)in_sizes; (void)n_in; (void)out_size; (void)ws_size;
  const float* x = (const float*)d_in[0];
  const int* eidx = (const int*)d_in[1];
  const int* esrc = eidx;
  const int* edst = eidx + N_EDGES;
  const float* eattr = (const float*)d_in[2];
  const float* W_enc = (const float*)d_in[3];
  const float* b_enc = (const float*)d_in[4];
  const float* We1 = (const float*)d_in[5];
  const float* be1 = (const float*)d_in[6];
  const float* W11 = (const float*)d_in[7];
  const float* b11 = (const float*)d_in[8];
  const float* W12 = (const float*)d_in[9];
  const float* b12 = (const float*)d_in[10];
  const float* eps1 = (const float*)d_in[11];
  const float* We2 = (const float*)d_in[12];
  const float* be2 = (const float*)d_in[13];
  const float* W21 = (const float*)d_in[14];
  const float* b21 = (const float*)d_in[15];
  const float* W22 = (const float*)d_in[16];
  const float* b22 = (const float*)d_in[17];
  const float* eps2 = (const float*)d_in[18];

  char* ws = (char*)d_ws;
  size_t o = 0;
  unsigned short* wt = (unsigned short*)(ws + o); o += 163840;
  unsigned short* hB = (unsigned short*)(ws + o); o += 51200000ull;
  unsigned short* bufZ = (unsigned short*)(ws + o); o += 51200000ull;
  float* eaC = (float*)(ws + o); o += 38400000ull;
  int* off = (int*)(ws + o); o += ((N_NODES + 1) * 4 + 15) / 16 * 16;
  int* cursor = (int*)(ws + o); o += ((size_t)N_NODES * 4 + 15) / 16 * 16;
  int* srcs = (int*)(ws + o); o += (size_t)N_EDGES * 4;
  int* partial = (int*)(ws + o); o += (SCAN_BLOCKS * 4 + 15) / 16 * 16;
  int* waveStart = (int*)(ws + o); o += (size_t)(NWAVES + 1) * 4;

  unsigned short* Wt_enc = wt;
  unsigned short* Wt11 = wt + 16384;
  unsigned short* Wt12 = wt + 2 * 16384;
  unsigned short* Wt21 = wt + 3 * 16384;
  unsigned short* Wt22 = wt + 4 * 16384;

  hipMemsetAsync(off, 0, (N_NODES + 1) * sizeof(int), stream);
  prep_kernel<<<dim3(16, 5), 256, 0, stream>>>(W_enc, W11, W12, W21, W22, wt);

  // h0 = relu(x @ W_enc + b_enc) -> bf16
  mlp_kernel<<<3125, 256, 0, stream>>>(x, 0, Wt_enc, b_enc, Wt_enc, b_enc, 0, 1, hB);

  hist_kernel<<<(N_EDGES + 255) / 256, 256, 0, stream>>>(edst, off, N_EDGES);
  scan_sum_kernel<<<SCAN_BLOCKS, 256, 0, stream>>>(off, partial, N_NODES);
  scan_partials_kernel<<<1, 256, 0, stream>>>(partial, off, SCAN_BLOCKS, N_NODES);
  scan_apply_kernel<<<SCAN_BLOCKS, 256, 0, stream>>>(partial, off, cursor, N_NODES);
  partition_kernel<<<(NWAVES + 256) / 256, 256, 0, stream>>>(off, waveStart);
  scatter_kernel<<<(N_EDGES + 255) / 256, 256, 0, stream>>>(edst, esrc, eattr, cursor, srcs, eaC,
                                                            N_EDGES);

  // conv1
  agg_z_kernel<<<GRID_AGG, 256, 0, stream>>>(hB, off, waveStart, srcs, eaC, We1, be1, eps1, bufZ);
  mlp_kernel<<<3125, 256, 0, stream>>>(bufZ, 1, Wt11, b11, Wt12, b12, 1, 1, hB);
  // conv2
  agg_z_kernel<<<GRID_AGG, 256, 0, stream>>>(hB, off, waveStart, srcs, eaC, We2, be2, eps2, bufZ);
  mlp_kernel<<<3125, 256, 0, stream>>>(bufZ, 1, Wt21, b21, Wt22, b22, 1, 0, d_out);
}